// Round 10
// baseline (2636.301 us; speedup 1.0000x reference)
//
#include <hip/hip_runtime.h>

// TimeLSTM persistent kernel for MI355X (gfx950).  B=128, S=512, I=256, H=512.
// 256 blocks x 256 threads, plain launch (grid == CU count -> co-resident).
//   band  q = blockIdx%8 -> batch rows [q*16, q*16+16)
//   slice s = blockIdx/8 -> H columns [s*16, s*16+16)
// Weight-stationary (112 VGPRs of bf16 B-fragments per wave).
//
// Round-10: TWO-SUBGROUP OFFSET PIPELINE. Evidence R6-R9: no latency shaving
// of any single leg helps; the step is bound by exposed flag propagation +
// detect (~4000cy/step). Fix: split the band into two independent
// recurrences A = rows 0-7, B = rows 8-15 (same weights, same LDS tile,
// rows 0-7 / 8-15). Pipeline per iteration:
//   P1 MFMA(full tile, keep quad<2 = A rows)
//   P2 gates_A+store_A (waves 2-3, vmcnt drain)  ||  wave0 polls flag_B(t)
//      raw-bar; tid0: flag_A := t+1
//   P4 issue B hc(t) loads + xA(t+1) loads; out_A; pack xB; fill B half; bar
//   P5 MFMA(full tile, keep quad>=2 = B rows)
//   P6 gates_B+store_B (vmcnt)  ||  wave0 polls flag_A(t+1)
//      raw-bar; tid0: flag_B := t+1
//   P8 issue A hc(t+1) loads; out_B; xB(t+1) loads; pack xA; fill A half; bar
// Every poll fires ~2000cy after the flags were stored -> propagation hides
// under the other sub-group's MFMA phase. Per-sub-group protocol is verbatim
// R3 (ack-then-flag agent scope, single wave-0 poll, s_sleep(2)): no new hang
// modes, no added poll traffic. Cost: MFMA/LDS pass x2 (half discarded,
// ~+1300cy) -- far less than the ~4000cy of sync it hides.
// Discarded-half safety: M-rows never mix in GEMM; garbage rows 8-15 (stale/
// uninit) only affect discarded accumulator rows (quad>=2 in pass A etc).

#define Bq 128
#define Sq 512
#define Iq 256
#define Hq 512

typedef __bf16  bf16x8  __attribute__((ext_vector_type(8)));
typedef float   floatx4 __attribute__((ext_vector_type(4)));
typedef unsigned short ushort;
typedef ushort  ushort8 __attribute__((ext_vector_type(8)));
typedef unsigned long long u64;

__device__ __forceinline__ ushort f2bf(float f) {
    union { float f; unsigned u; } v; v.f = f;
    unsigned r = v.u + 0x7fffu + ((v.u >> 16) & 1u);   // RNE
    return (ushort)(r >> 16);
}

__device__ __forceinline__ float sigm(float x) { return 1.f / (1.f + __expf(-x)); }
__device__ __forceinline__ float tanh_fast(float x) {
    float e = __expf(2.f * x);
    return 1.f - 2.f / (e + 1.f);
}

__device__ __forceinline__ bf16x8 pack8(float4 a, float4 b) {
    ushort8 v;
    v[0] = f2bf(a.x); v[1] = f2bf(a.y); v[2] = f2bf(a.z); v[3] = f2bf(a.w);
    v[4] = f2bf(b.x); v[5] = f2bf(b.y); v[6] = f2bf(b.z); v[7] = f2bf(b.w);
    return __builtin_bit_cast(bf16x8, v);
}

// Raw workgroup rendezvous: no implicit vmcnt/lgkm drain.
__device__ __forceinline__ void block_bar() {
    asm volatile("" ::: "memory");
    __builtin_amdgcn_s_barrier();
    asm volatile("" ::: "memory");
}

// ---------------- main persistent kernel ----------------
__global__ __launch_bounds__(256, 1) void lstm_kernel(
    const float* __restrict__ xin,
    const float* __restrict__ tsp,
    const float* __restrict__ Ww, const float* __restrict__ Wb,
    const float* __restrict__ Uw, const float* __restrict__ Ub,
    const float* __restrict__ Dw, const float* __restrict__ Db,
    unsigned* __restrict__ hcbuf,   // [parity][band][sub][ h:2048 | c:2048 ] u32
    unsigned* __restrict__ slots,   // [band][128]: [0,32) flagA, [64,96) flagB
    float* __restrict__ out)
{
    __shared__ ushort h_s[16 * 520];   // rows 0-7 = sub A, 8-15 = sub B
    __shared__ ushort c_s[16 * 520];
    __shared__ ushort x_s[16 * 264];
    __shared__ float  gb[4 * 128];     // one sub at a time (reused A/B)
    __shared__ float  gd[4 * 128];
    __shared__ float  bias_g[64];
    __shared__ float  bias_d[16];

    const int tid  = threadIdx.x;
    const int lane = tid & 63;
    const int wv   = tid >> 6;         // wave id == gate id
    const int n    = lane & 15;
    const int quad = lane >> 4;
    const int q    = blockIdx.x & 7;   // band
    const int s    = blockIdx.x >> 3;  // column slice 0..31
    const int jj   = s * 16;

    // ---- stationary B-fragments (identical to R3) ----
    bf16x8 bW[16], bU[8], bD[4];
    {
        const int Rw = wv * Hq + jj + n;
        #pragma unroll
        for (int kk = 0; kk < 16; ++kk) {
            const float4* p = (const float4*)(Ww + (size_t)Rw * Hq + kk * 32 + quad * 8);
            bW[kk] = pack8(p[0], p[1]);
        }
        #pragma unroll
        for (int kk = 0; kk < 8; ++kk) {
            const float4* p = (const float4*)(Uw + (size_t)Rw * Iq + kk * 32 + quad * 8);
            bU[kk] = pack8(p[0], p[1]);
        }
        const int Rd = jj + n;
        #pragma unroll
        for (int kq = 0; kq < 4; ++kq) {
            const float4* p = (const float4*)(Dw + (size_t)Rd * Hq + (wv * 4 + kq) * 32 + quad * 8);
            bD[kq] = pack8(p[0], p[1]);
        }
    }
    if (tid < 64)
        bias_g[tid] = Wb[(tid >> 4) * Hq + jj + (tid & 15)] + Ub[(tid >> 4) * Hq + jj + (tid & 15)];
    if (tid >= 64 && tid < 80)
        bias_d[tid - 64] = Db[jj + (tid - 64)];
    __syncthreads();

    // gate threads: waves 2-3 handle the 128 cells of the active sub
    const int gt    = tid & 127;       // cell id (valid when tid>=128)
    const int gjrow = gt >> 4;         // batch row within sub, 0..7
    const int gj    = tid & 15;        // H col within slice

    float cA = 0.f, cB = 0.f, hA = 0.f, hB = 0.f;

    const ushort* hp = &h_s[n * 520 + quad * 8];
    const ushort* cp = &c_s[n * 520 + quad * 8];
    const ushort* xp = &x_s[n * 264 + quad * 8];

    unsigned* flagA = &slots[q * 128 + s];
    unsigned* flagB = &slots[q * 128 + 64 + s];
    const unsigned* pollA = &slots[q * 128 + (lane & 31)];
    const unsigned* pollB = &slots[q * 128 + 64 + (lane & 31)];

    // x staging: thread -> row (tid>>5) in sub, cols [(tid&31)*8, +8)
    const int xrow = tid >> 5;
    const int xcol = (tid & 31) * 8;
    const float* xbaseA = xin + ((size_t)(q * 16 + xrow) * Sq) * Iq + xcol;
    const float* xbaseB = xin + ((size_t)(q * 16 + 8 + xrow) * Sq) * Iq + xcol;
    ushort* xdstA = &x_s[xrow * 264 + xcol];
    ushort* xdstB = &x_s[(8 + xrow) * 264 + xcol];

    float4 xA0, xA1, xB0, xB1;
    { const float4* p = (const float4*)xbaseA; xA0 = p[0]; xA1 = p[1]; }
    { const float4* p = (const float4*)xbaseB; xB0 = p[0]; xB1 = p[1]; }

    // ---- prologue: fill A half from zeroed parity-0 + pack xA(0) ----
    {
        const u64* hc = (const u64*)(hcbuf + (size_t)(q * 2 + 0) * 4096);
        u64 hv[4], cv[4];
        #pragma unroll
        for (int k = 0; k < 4; ++k)
            hv[k] = __hip_atomic_load(hc + k * 256 + tid, __ATOMIC_RELAXED, __HIP_MEMORY_SCOPE_AGENT);
        #pragma unroll
        for (int k = 0; k < 4; ++k)
            cv[k] = __hip_atomic_load(hc + 1024 + k * 256 + tid, __ATOMIC_RELAXED, __HIP_MEMORY_SCOPE_AGENT);
        *(bf16x8*)xdstA = pack8(xA0, xA1);
        #pragma unroll
        for (int k = 0; k < 4; ++k) {
            const int m   = k * 256 + tid;       // u64 idx in [0,1024)
            const int row = m >> 7;              // 0..7
            const int col = (4 * m) & 511;
            *(u64*)&h_s[row * 520 + col] = hv[k];
            *(u64*)&c_s[row * 520 + col] = cv[k];
        }
    }
    __syncthreads();

    for (int t = 0; t < Sq; ++t) {
        float ttA = 0.f, ttB = 0.f;
        if (tid >= 128) {
            ttA = tsp[(size_t)(q * 16 + gjrow) * Sq + t];
            ttB = tsp[(size_t)(q * 16 + 8 + gjrow) * Sq + t];
        }

        // ---- P1: full MFMA pass, keep A rows (quad<2) ----
        {
            floatx4 accW = {0.f,0.f,0.f,0.f}, accU = {0.f,0.f,0.f,0.f}, accD = {0.f,0.f,0.f,0.f};
            #pragma unroll
            for (int kk = 0; kk < 16; ++kk) {
                bf16x8 ah = *(const bf16x8*)(hp + kk * 32);
                accW = __builtin_amdgcn_mfma_f32_16x16x32_bf16(ah, bW[kk], accW, 0, 0, 0);
                if (kk < 8) {
                    bf16x8 ax = *(const bf16x8*)(xp + kk * 32);
                    accU = __builtin_amdgcn_mfma_f32_16x16x32_bf16(ax, bU[kk], accU, 0, 0, 0);
                }
                if ((kk >> 2) == wv) {
                    bf16x8 ac = *(const bf16x8*)(cp + kk * 32);
                    accD = __builtin_amdgcn_mfma_f32_16x16x32_bf16(ac, bD[kk & 3], accD, 0, 0, 0);
                }
            }
            accW += accU;
            if (quad < 2) {
                #pragma unroll
                for (int r2 = 0; r2 < 4; ++r2) {
                    gb[wv * 128 + (quad * 4 + r2) * 16 + n] = accW[r2];
                    gd[wv * 128 + (quad * 4 + r2) * 16 + n] = accD[r2];
                }
            }
        }
        __syncthreads();                         // gb/gd (A) ready

        // ---- P2: gates_A + store_A (waves 2-3)  ||  wave0 polls flag_B(t) ----
        if (tid >= 128) {
            float pf = gb[gt]       + bias_g[gj];
            float pi = gb[128 + gt] + bias_g[16 + gj];
            float po = gb[256 + gt] + bias_g[32 + gj];
            float pc = gb[384 + gt] + bias_g[48 + gj];
            float csum = gd[gt] + gd[128 + gt] + gd[256 + gt] + gd[384 + gt] + bias_d[gj];
            float c_s1  = tanh_fast(csum);
            float c_adj = cA - c_s1 + c_s1 * ttA;
            float fg = sigm(pf), ig = sigm(pi), og = sigm(po), cg = sigm(pc);
            float c_new = fg * c_adj + ig * cg;
            hA = og * tanh_fast(c_new);
            cA = c_new;
            unsigned my    = ((unsigned)f2bf(c_new) << 16) | (unsigned)f2bf(hA);
            unsigned other = __shfl_xor(my, 1);
            unsigned* dst  = hcbuf + ((size_t)((t + 1) & 1) * 16 + q * 2 + 0) * 4096;
            const int pidx = gjrow * 256 + ((jj + gj) >> 1);
            if ((gj & 1) == 0)
                __hip_atomic_store(dst + pidx, ((other & 0xFFFFu) << 16) | (my & 0xFFFFu),
                                   __ATOMIC_RELAXED, __HIP_MEMORY_SCOPE_AGENT);
            else
                __hip_atomic_store(dst + 2048 + pidx, (my & 0xFFFF0000u) | (other >> 16),
                                   __ATOMIC_RELAXED, __HIP_MEMORY_SCOPE_AGENT);
            asm volatile("s_waitcnt vmcnt(0)" ::: "memory");   // A stores ack'd
        } else if (wv == 0 && t > 0) {
            const unsigned tgt = (unsigned)t;    // flag_B stored last iter P6
            for (;;) {
                unsigned vv = __hip_atomic_load(pollB, __ATOMIC_RELAXED, __HIP_MEMORY_SCOPE_AGENT);
                if (__all(vv >= tgt)) break;
                __builtin_amdgcn_s_sleep(2);
            }
        }
        block_bar();
        if (tid == 0)
            __hip_atomic_store(flagA, (unsigned)(t + 1), __ATOMIC_RELAXED, __HIP_MEMORY_SCOPE_AGENT);

        // ---- P4: B hc(t) loads; out_A; xA(t+1) issue; pack xB; fill B half ----
        {
            const u64* hc = (const u64*)(hcbuf + ((size_t)(t & 1) * 16 + q * 2 + 1) * 4096);
            u64 hv[4], cv[4];
            #pragma unroll
            for (int k = 0; k < 4; ++k)
                hv[k] = __hip_atomic_load(hc + k * 256 + tid, __ATOMIC_RELAXED, __HIP_MEMORY_SCOPE_AGENT);
            #pragma unroll
            for (int k = 0; k < 4; ++k)
                cv[k] = __hip_atomic_load(hc + 1024 + k * 256 + tid, __ATOMIC_RELAXED, __HIP_MEMORY_SCOPE_AGENT);
            if (tid >= 128)   // deferred out_A: ack hides until P6's drain
                out[((size_t)(q * 16 + gjrow) * Sq + t) * Hq + jj + gj] = hA;
            if (t < Sq - 1) {
                const float4* p = (const float4*)(xbaseA + (size_t)(t + 1) * Iq);
                xA0 = p[0]; xA1 = p[1];
            }
            *(bf16x8*)xdstB = pack8(xB0, xB1);
            #pragma unroll
            for (int k = 0; k < 4; ++k) {
                const int m   = k * 256 + tid;
                const int row = 8 + (m >> 7);
                const int col = (4 * m) & 511;
                *(u64*)&h_s[row * 520 + col] = hv[k];
                *(u64*)&c_s[row * 520 + col] = cv[k];
            }
        }
        __syncthreads();                         // B tile ready

        // ---- P5: full MFMA pass, keep B rows (quad>=2) ----
        {
            floatx4 accW = {0.f,0.f,0.f,0.f}, accU = {0.f,0.f,0.f,0.f}, accD = {0.f,0.f,0.f,0.f};
            #pragma unroll
            for (int kk = 0; kk < 16; ++kk) {
                bf16x8 ah = *(const bf16x8*)(hp + kk * 32);
                accW = __builtin_amdgcn_mfma_f32_16x16x32_bf16(ah, bW[kk], accW, 0, 0, 0);
                if (kk < 8) {
                    bf16x8 ax = *(const bf16x8*)(xp + kk * 32);
                    accU = __builtin_amdgcn_mfma_f32_16x16x32_bf16(ax, bU[kk], accU, 0, 0, 0);
                }
                if ((kk >> 2) == wv) {
                    bf16x8 ac = *(const bf16x8*)(cp + kk * 32);
                    accD = __builtin_amdgcn_mfma_f32_16x16x32_bf16(ac, bD[kk & 3], accD, 0, 0, 0);
                }
            }
            accW += accU;
            if (quad >= 2) {
                #pragma unroll
                for (int r2 = 0; r2 < 4; ++r2) {
                    gb[wv * 128 + ((quad - 2) * 4 + r2) * 16 + n] = accW[r2];
                    gd[wv * 128 + ((quad - 2) * 4 + r2) * 16 + n] = accD[r2];
                }
            }
        }
        __syncthreads();                         // gb/gd (B) ready

        // ---- P6: gates_B + store_B (waves 2-3)  ||  wave0 polls flag_A(t+1) ----
        if (tid >= 128) {
            float pf = gb[gt]       + bias_g[gj];
            float pi = gb[128 + gt] + bias_g[16 + gj];
            float po = gb[256 + gt] + bias_g[32 + gj];
            float pc = gb[384 + gt] + bias_g[48 + gj];
            float csum = gd[gt] + gd[128 + gt] + gd[256 + gt] + gd[384 + gt] + bias_d[gj];
            float c_s1  = tanh_fast(csum);
            float c_adj = cB - c_s1 + c_s1 * ttB;
            float fg = sigm(pf), ig = sigm(pi), og = sigm(po), cg = sigm(pc);
            float c_new = fg * c_adj + ig * cg;
            hB = og * tanh_fast(c_new);
            cB = c_new;
            unsigned my    = ((unsigned)f2bf(c_new) << 16) | (unsigned)f2bf(hB);
            unsigned other = __shfl_xor(my, 1);
            unsigned* dst  = hcbuf + ((size_t)((t + 1) & 1) * 16 + q * 2 + 1) * 4096;
            const int pidx = gjrow * 256 + ((jj + gj) >> 1);
            if ((gj & 1) == 0)
                __hip_atomic_store(dst + pidx, ((other & 0xFFFFu) << 16) | (my & 0xFFFFu),
                                   __ATOMIC_RELAXED, __HIP_MEMORY_SCOPE_AGENT);
            else
                __hip_atomic_store(dst + 2048 + pidx, (my & 0xFFFF0000u) | (other >> 16),
                                   __ATOMIC_RELAXED, __HIP_MEMORY_SCOPE_AGENT);
            asm volatile("s_waitcnt vmcnt(0)" ::: "memory");   // B stores ack'd
        } else if (wv == 0 && t < Sq - 1) {
            const unsigned tgt = (unsigned)(t + 1);  // flag_A stored at P2
            for (;;) {
                unsigned vv = __hip_atomic_load(pollA, __ATOMIC_RELAXED, __HIP_MEMORY_SCOPE_AGENT);
                if (__all(vv >= tgt)) break;
                __builtin_amdgcn_s_sleep(2);
            }
        }
        block_bar();
        if (tid == 0)
            __hip_atomic_store(flagB, (unsigned)(t + 1), __ATOMIC_RELAXED, __HIP_MEMORY_SCOPE_AGENT);

        // ---- P8: A hc(t+1) loads; out_B; xB(t+1) issue; pack xA; fill A half ----
        if (t < Sq - 1) {
            const u64* hc = (const u64*)(hcbuf + ((size_t)((t + 1) & 1) * 16 + q * 2 + 0) * 4096);
            u64 hv[4], cv[4];
            #pragma unroll
            for (int k = 0; k < 4; ++k)
                hv[k] = __hip_atomic_load(hc + k * 256 + tid, __ATOMIC_RELAXED, __HIP_MEMORY_SCOPE_AGENT);
            #pragma unroll
            for (int k = 0; k < 4; ++k)
                cv[k] = __hip_atomic_load(hc + 1024 + k * 256 + tid, __ATOMIC_RELAXED, __HIP_MEMORY_SCOPE_AGENT);
            if (tid >= 128)
                out[((size_t)(q * 16 + 8 + gjrow) * Sq + t) * Hq + jj + gj] = hB;
            {
                const float4* p = (const float4*)(xbaseB + (size_t)(t + 1) * Iq);
                xB0 = p[0]; xB1 = p[1];
            }
            *(bf16x8*)xdstA = pack8(xA0, xA1);   // xA(t+1) regs issued at P4
            #pragma unroll
            for (int k = 0; k < 4; ++k) {
                const int m   = k * 256 + tid;
                const int row = m >> 7;          // 0..7
                const int col = (4 * m) & 511;
                *(u64*)&h_s[row * 520 + col] = hv[k];
                *(u64*)&c_s[row * 520 + col] = cv[k];
            }
            __syncthreads();                     // A tile ready for next iter
        } else {
            if (tid >= 128)
                out[((size_t)(q * 16 + 8 + gjrow) * Sq + t) * Hq + jj + gj] = hB;
        }
    }
}

extern "C" void kernel_launch(void* const* d_in, const int* in_sizes, int n_in,
                              void* d_out, int out_size, void* d_ws, size_t ws_size,
                              hipStream_t stream) {
    const float* inputs = (const float*)d_in[0];
    const float* tsp    = (const float*)d_in[1];
    const float* Ww     = (const float*)d_in[2];
    const float* Wb     = (const float*)d_in[3];
    const float* Uw     = (const float*)d_in[4];
    const float* Ub     = (const float*)d_in[5];
    const float* Dw     = (const float*)d_in[6];
    const float* Db     = (const float*)d_in[7];
    float* out = (float*)d_out;

    char* ws = (char*)d_ws;
    // layout: [0,512K) hcbuf (2 par x 8 band x 2 sub x 4096 u32) | [512K,516K) slots
    unsigned* hcbuf = (unsigned*)ws;
    unsigned* slots = (unsigned*)(ws + 524288);

    hipMemsetAsync(ws, 0, 262144, stream);          // parity-0 hc = 0 (h0 = c0 = 0)
    hipMemsetAsync(ws + 524288, 0, 4096, stream);   // 8 bands x 128 flag slots = 0

    lstm_kernel<<<dim3(256), dim3(256), 0, stream>>>(
        inputs, tsp, Ww, Wb, Uw, Ub, Dw, Db, hcbuf, slots, out);
}